// Round 8
// baseline (137.896 us; speedup 1.0000x reference)
//
#include <hip/hip_runtime.h>
#include <math.h>

// QuanvolutionHybridGraphQL:
//   q   = cos(2x2 patches of 28x28 img)            -> (B,196,4)
//   qn  = q / (||q||_2 + 1e-12)
//   fid = (qn . qn^T)^2                             -> (B,196,196)
//   adj = fid>=0.8 ? 1 : fid>=0.5 ? 0.5 : 0 ; diag=0
//   logits = (mean_n q @ W1 + b1) @ W2 + b2         -> (B,10)
// adj is 629 MB fp32 -> HBM-write bound. Fill calibrates ~6.6 TB/s (~97us
// floor). Ladder: R1 scalar 179 | R3 f4 NT 140 | R4 plain 150 | R5 784B 179
// | R7 all-aligned 137.5. Alignment ~= noise; the working levers are
// instructions-per-byte and NT. R8: cut per-f4 work ~20%: both images of
// the pair per iteration (shared bookkeeping, 2 store streams), branchless
// incremental n/m%49 (256=5*49+11) replacing magic-div, AoS qn copy so the
// c-side is one ds_read_b128 (LDS ops 8->5). Store pattern unchanged.

#define NP    196
#define NPIX  784
#define BLK   256
#define VPR   (NP / 4)            // 49 float4 per row
#define F4PI  (NP * NP / 4)       // 9604 float4 per image
#define F4PP  (2 * F4PI)          // 19208 float4 per image pair

typedef float f32x4 __attribute__((ext_vector_type(4)));

__global__ __launch_bounds__(BLK) void quanv_kernel(
    const float* __restrict__ x,
    const float* __restrict__ W1, const float* __restrict__ b1,
    const float* __restrict__ W2, const float* __restrict__ b2,
    float* __restrict__ logits, float* __restrict__ adj)
{
    __shared__ float q4[2][NP][4];                   // q, patch-major
    __shared__ __align__(16) float qnT[2][4][NP];    // qn dim-major (v-side)
    __shared__ __align__(16) float qnA[2][NP][4];    // qn AoS       (c-side)
    __shared__ float pooled[2][4];

    const int g   = blockIdx.x;        // image pair index
    const int tid = threadIdx.x;
    const int w   = tid >> 6;          // wave 0..3
    const int l   = tid & 63;          // lane 0..63
    const float* imgs = x + (size_t)g * (2 * NPIX);

    // 1) coalesced pixel load (both images) -> cos -> q in LDS
    for (int p = tid; p < 2 * NPIX; p += BLK) {
        int im = (p >= NPIX);
        int pp = p - im * NPIX;
        int r = pp / 28;
        int c = pp - r * 28;
        int n  = (r >> 1) * 14 + (c >> 1);
        int dd = ((r & 1) << 1) | (c & 1);
        q4[im][n][dd] = cosf(imgs[p]);
    }
    __syncthreads();

    // 2) per-patch L2-normalize into BOTH layouts (strided: 392 > 256!)
    for (int t = tid; t < 2 * NP; t += BLK) {
        int im = (t >= NP);
        int n  = t - im * NP;
        float a0 = q4[im][n][0], a1 = q4[im][n][1];
        float a2 = q4[im][n][2], a3 = q4[im][n][3];
        float inv = 1.0f / (sqrtf(a0*a0 + a1*a1 + a2*a2 + a3*a3) + 1e-12f);
        float b0 = a0*inv, b1v = a1*inv, b2v = a2*inv, b3 = a3*inv;
        qnT[im][0][n] = b0;
        qnT[im][1][n] = b1v;
        qnT[im][2][n] = b2v;
        qnT[im][3][n] = b3;
        f32x4 aos; aos.x = b0; aos.y = b1v; aos.z = b2v; aos.w = b3;
        *reinterpret_cast<f32x4*>(&qnA[im][n][0]) = aos;
    }

    // 3) pooled = mean_n q  (wave 0 -> image 0, wave 1 -> image 1)
    if (w < 2) {
        float s0 = 0.f, s1 = 0.f, s2 = 0.f, s3 = 0.f;
        for (int n = l; n < NP; n += 64) {
            s0 += q4[w][n][0]; s1 += q4[w][n][1];
            s2 += q4[w][n][2]; s3 += q4[w][n][3];
        }
        #pragma unroll
        for (int off = 32; off >= 1; off >>= 1) {
            s0 += __shfl_down(s0, off);
            s1 += __shfl_down(s1, off);
            s2 += __shfl_down(s2, off);
            s3 += __shfl_down(s3, off);
        }
        if (l == 0) {
            pooled[w][0] = s0 * (1.0f / NP);
            pooled[w][1] = s1 * (1.0f / NP);
            pooled[w][2] = s2 * (1.0f / NP);
            pooled[w][3] = s3 * (1.0f / NP);
        }
    }
    __syncthreads();

    // 4) tiny MLP for both images: threads 0..9 -> im 0, 10..19 -> im 1
    if (tid < 20) {
        int im = (tid >= 10);
        int j  = tid - im * 10;
        float p0 = pooled[im][0], p1 = pooled[im][1];
        float p2 = pooled[im][2], p3 = pooled[im][3];
        float acc = b2[j];
        #pragma unroll
        for (int k = 0; k < 32; ++k) {
            float h = b1[k] + p0 * W1[0*32 + k] + p1 * W1[1*32 + k]
                            + p2 * W1[2*32 + k] + p3 * W1[3*32 + k];
            acc += h * W2[k*10 + j];
        }
        logits[(size_t)(2*g + im) * 10 + j] = acc;
    }

    // 5) adj: BOTH images per iteration; flat loop; aligned 1KiB NT stores.
    //    n = e4/49, m0i = e4%49 maintained incrementally (256 = 5*49 + 11).
    f32x4* out0 = reinterpret_cast<f32x4*>(adj) + (size_t)g * F4PP;
    f32x4* out1 = out0 + F4PI;

    int n   = tid / VPR;          // 0..5 at entry
    int m0i = tid - n * VPR;      // 0..48

    for (int e4 = tid; e4 < F4PI; e4 += BLK) {
        const int m0 = m0i * 4;

        f32x4 cA = *reinterpret_cast<const f32x4*>(&qnA[0][n][0]);
        f32x4 cB = *reinterpret_cast<const f32x4*>(&qnA[1][n][0]);
        f32x4 vA0 = *reinterpret_cast<const f32x4*>(&qnT[0][0][m0]);
        f32x4 vA1 = *reinterpret_cast<const f32x4*>(&qnT[0][1][m0]);
        f32x4 vA2 = *reinterpret_cast<const f32x4*>(&qnT[0][2][m0]);
        f32x4 vA3 = *reinterpret_cast<const f32x4*>(&qnT[0][3][m0]);
        f32x4 vB0 = *reinterpret_cast<const f32x4*>(&qnT[1][0][m0]);
        f32x4 vB1 = *reinterpret_cast<const f32x4*>(&qnT[1][1][m0]);
        f32x4 vB2 = *reinterpret_cast<const f32x4*>(&qnT[1][2][m0]);
        f32x4 vB3 = *reinterpret_cast<const f32x4*>(&qnT[1][3][m0]);

        f32x4 dA = cA.x*vA0 + cA.y*vA1 + cA.z*vA2 + cA.w*vA3;
        f32x4 dB = cB.x*vB0 + cB.y*vB1 + cB.z*vB2 + cB.w*vB3;
        f32x4 fA = dA * dA;
        f32x4 fB = dB * dB;

        f32x4 oA, oB;
        oA.x = (fA.x >= 0.8f) ? 1.0f : ((fA.x >= 0.5f) ? 0.5f : 0.0f);
        oA.y = (fA.y >= 0.8f) ? 1.0f : ((fA.y >= 0.5f) ? 0.5f : 0.0f);
        oA.z = (fA.z >= 0.8f) ? 1.0f : ((fA.z >= 0.5f) ? 0.5f : 0.0f);
        oA.w = (fA.w >= 0.8f) ? 1.0f : ((fA.w >= 0.5f) ? 0.5f : 0.0f);
        oB.x = (fB.x >= 0.8f) ? 1.0f : ((fB.x >= 0.5f) ? 0.5f : 0.0f);
        oB.y = (fB.y >= 0.8f) ? 1.0f : ((fB.y >= 0.5f) ? 0.5f : 0.0f);
        oB.z = (fB.z >= 0.8f) ? 1.0f : ((fB.z >= 0.5f) ? 0.5f : 0.0f);
        oB.w = (fB.w >= 0.8f) ? 1.0f : ((fB.w >= 0.5f) ? 0.5f : 0.0f);

        // zero diagonal (same (n, m0) for both images)
        bool d0 = (m0 + 0 == n), d1 = (m0 + 1 == n);
        bool d2 = (m0 + 2 == n), d3 = (m0 + 3 == n);
        oA.x = d0 ? 0.0f : oA.x;  oB.x = d0 ? 0.0f : oB.x;
        oA.y = d1 ? 0.0f : oA.y;  oB.y = d1 ? 0.0f : oB.y;
        oA.z = d2 ? 0.0f : oA.z;  oB.z = d2 ? 0.0f : oB.z;
        oA.w = d3 ? 0.0f : oA.w;  oB.w = d3 ? 0.0f : oB.w;

        __builtin_nontemporal_store(oA, &out0[e4]);
        __builtin_nontemporal_store(oB, &out1[e4]);

        // branchless increment: e4 += 256  =>  n += 5, m0i += 11 (mod 49)
        m0i += 11;
        n   += 5;
        int wrap = (m0i >= VPR);
        m0i = wrap ? m0i - VPR : m0i;
        n  += wrap;
    }
}

extern "C" void kernel_launch(void* const* d_in, const int* in_sizes, int n_in,
                              void* d_out, int out_size, void* d_ws, size_t ws_size,
                              hipStream_t stream) {
    const float* x  = (const float*)d_in[0];
    const float* W1 = (const float*)d_in[1];
    const float* b1 = (const float*)d_in[2];
    const float* W2 = (const float*)d_in[3];
    const float* b2 = (const float*)d_in[4];

    const int B = in_sizes[0] / NPIX;          // 4096
    float* logits = (float*)d_out;             // B*10
    float* adj    = logits + (size_t)B * 10;   // B*196*196

    quanv_kernel<<<B / 2, BLK, 0, stream>>>(x, W1, b1, W2, b2, logits, adj);
}